// Round 8
// baseline (466.378 us; speedup 1.0000x reference)
//
#include <hip/hip_runtime.h>
#include <math.h>

#define BATCH 8
#define NPTS 4096
#define CHAN 128
#define KNN 16
#define SPLIT 4
#define SCHUNK (NPTS / SPLIT)   // 1024 sorted points per split
#define NGRP (NPTS / 16)        // 256 groups of 16 per batch
#define GPS (NGRP / SPLIT)      // 64 groups per split
#define RSPLIT 4
#define RCHUNK (NPTS / RSPLIT)
#define PRUNE_EPS 1e-2f         // >> 5e-5 max fp32 d2 rounding error

typedef unsigned long long u64;

// Monotone key: ascending u64 == (d2 ascending, idx ascending).
__device__ __forceinline__ u64 pack_key(float d2, int idx) {
  unsigned b = __float_as_uint(d2);
  b ^= (unsigned)((int)b >> 31) | 0x80000000u;
  return ((u64)b << 32) | (unsigned)idx;
}
// Inverse of the high-word map (sentinel 0xFFFFFFFF -> NaN -> never prunes).
__device__ __forceinline__ float unmap_hi(unsigned b) {
  unsigned r = (b & 0x80000000u) ? (b ^ 0x80000000u) : ~b;
  return __uint_as_float(r);
}

__device__ __forceinline__ void ce_asc(u64& x, u64& y) {
  bool sw = y < x;
  u64 lo = sw ? y : x;
  u64 hi = sw ? x : y;
  x = lo; y = hi;
}

__device__ __forceinline__ void bitonic_sort16(u64 a[16]) {
#pragma unroll
  for (int k = 2; k <= 16; k <<= 1) {
#pragma unroll
    for (int j = k >> 1; j > 0; j >>= 1) {
#pragma unroll
      for (int i = 0; i < 16; ++i) {
        int l = i ^ j;
        if (l > i) {
          if ((i & k) == 0) ce_asc(a[i], a[l]);
          else              ce_asc(a[l], a[i]);
        }
      }
    }
  }
}

// T,A sorted asc -> T = lowest-16 of union, sorted. 16 min + 32 CE.
__device__ __forceinline__ void merge_keep16(u64 T[16], const u64 A[16]) {
  u64 nt[16];
#pragma unroll
  for (int i = 0; i < 16; ++i) {
    u64 a = A[15 - i];
    nt[i] = (a < T[i]) ? a : T[i];
  }
#pragma unroll
  for (int j = 8; j > 0; j >>= 1) {
#pragma unroll
    for (int i = 0; i < 16; ++i) {
      int l = i ^ j;
      if (l > i) ce_asc(nt[i], nt[l]);
    }
  }
#pragma unroll
  for (int i = 0; i < 16; ++i) T[i] = nt[i];
}

// ---------------------------------------------------------------------------
// Prep 1: counting rank of points by x ascending (ties -> lower index).
// ANY bijection works for correctness; x-sort gives spatial coherence.
// ---------------------------------------------------------------------------
__global__ __launch_bounds__(256) void xrank_kernel(
    const float* __restrict__ x, int* __restrict__ xrank) {
  const int b = blockIdx.x / (NPTS / 256);
  const int n = (blockIdx.x % (NPTS / 256)) * 256 + threadIdx.x;
  __shared__ float xs[NPTS];
  const float* xb = x + (size_t)b * 3 * NPTS;
  for (int i = threadIdx.x; i < NPTS; i += 256) xs[i] = xb[i];
  __syncthreads();
  const float xn = xs[n];
  int c = 0;
#pragma unroll 8
  for (int m = 0; m < NPTS; ++m) {
    float xm = xs[m];
    c += (xm < xn) || (xm == xn && m < n);
  }
  xrank[(size_t)b * NPTS + n] = c;
}

// ---------------------------------------------------------------------------
// Prep 2: scatter into sorted order; .w carries the ORIGINAL index bits.
// ---------------------------------------------------------------------------
__global__ __launch_bounds__(256) void build_sorted_kernel(
    const float* __restrict__ x, const int* __restrict__ xrank,
    float4* __restrict__ sorted4) {
  const int t = blockIdx.x * 256 + threadIdx.x;  // over B*N
  const int b = t / NPTS;
  const int n = t % NPTS;
  const float* xb = x + (size_t)b * 3 * NPTS;
  int r = xrank[t];
  sorted4[(size_t)b * NPTS + r] =
      make_float4(xb[n], xb[NPTS + n], xb[2 * NPTS + n], __int_as_float(n));
}

// ---------------------------------------------------------------------------
// Prep 3: per-group [16 sorted points] min/max x for pruning.
// ---------------------------------------------------------------------------
__global__ __launch_bounds__(256) void aabb_kernel(
    const float4* __restrict__ sorted4, float* __restrict__ gmin,
    float* __restrict__ gmax) {
  const int t = blockIdx.x * 256 + threadIdx.x;  // over B*NGRP = 2048
  const int b = t / NGRP;
  const int g = t % NGRP;
  const float4* p = sorted4 + (size_t)b * NPTS + g * 16;
  float mn = p[0].x, mx = p[0].x;
#pragma unroll
  for (int i = 1; i < 16; ++i) {
    float v = p[i].x;
    mn = fminf(mn, v);
    mx = fmaxf(mx, v);
  }
  gmin[t] = mn;
  gmax[t] = mx;
}

// ---------------------------------------------------------------------------
// Kernel 1a: pruned per-split 16-NN partials (sorted u64 keys, ORIG indices).
// grid: B * 16 qtiles * SPLIT = 512 blocks, block 256 (wave = 64 x-adjacent
// queries). Groups scanned nearest-first (wrap) so T[15] tightens early;
// group skipped iff ALL lanes prove min-x-dist^2 > d2(T[15]) + eps.
// Conservative: skipped candidates have formula-d2 strictly > T[15] ->
// exact top-16 set unchanged (rounding <= ~5e-5 << eps).
// ---------------------------------------------------------------------------
__global__ __attribute__((amdgpu_waves_per_eu(2, 2)))
__launch_bounds__(256) void knn_sorted_kernel(
    const float4* __restrict__ sorted4, const float* __restrict__ gmin,
    const float* __restrict__ gmax, u64* __restrict__ pkey) {
  const int s = blockIdx.x % SPLIT;
  const int qtile = (blockIdx.x / SPLIT) % 16;
  const int b = blockIdx.x / (SPLIT * 16);

  __shared__ float4 sp[SCHUNK];   // split's sorted points (16 KB)
  __shared__ float gmn[GPS], gmx[GPS];

  const float4* sb = sorted4 + (size_t)b * NPTS;
  for (int i = threadIdx.x; i < SCHUNK; i += 256)
    sp[i] = sb[s * SCHUNK + i];
  if (threadIdx.x < GPS) {
    gmn[threadIdx.x] = gmin[b * NGRP + s * GPS + threadIdx.x];
    gmx[threadIdx.x] = gmax[b * NGRP + s * GPS + threadIdx.x];
  }

  const int pos = qtile * 256 + threadIdx.x;  // sorted position of my query
  float4 p4 = sb[pos];
  const float ppx = p4.x, ppy = p4.y, ppz = p4.z;
  const float psq = __fadd_rn(
      __fadd_rn(__fmul_rn(ppx, ppx), __fmul_rn(ppy, ppy)),
      __fmul_rn(ppz, ppz));
  __syncthreads();

  u64 T[16];
#pragma unroll
  for (int i = 0; i < 16; ++i) T[i] = ~0ull;
  float thr = __int_as_float(0x7f800000);  // +inf: evaluate until T is real

  // start at the group nearest this tile's center, wrap within the split
  int g0 = qtile * 16 + 8 - s * GPS;
  g0 = min(max(g0, 0), GPS - 1);

  for (int gg = 0; gg < GPS; ++gg) {
    const int g = (g0 + gg) & (GPS - 1);
    // per-lane prune test on group's x-extent
    float dx = fmaxf(0.0f, fmaxf(gmn[g] - ppx, ppx - gmx[g]));
    float dx2 = dx * dx;
    bool needed = !(dx2 > thr + PRUNE_EPS);  // NaN/inf thr -> needed
    if (__any(needed)) {
      u64 A[16];
#pragma unroll
      for (int t = 0; t < 16; ++t) {
        float4 q = sp[g * 16 + t];
        float qsq = __fadd_rn(
            __fadd_rn(__fmul_rn(q.x, q.x), __fmul_rn(q.y, q.y)),
            __fmul_rn(q.z, q.z));
        // inner = ((x0*y0 + x1*y1) + x2*y2), fp32, no fma (numpy order)
        float inner = __fadd_rn(
            __fadd_rn(__fmul_rn(ppx, q.x), __fmul_rn(ppy, q.y)),
            __fmul_rn(ppz, q.z));
        // d2 = (sq_n + sq_m) - 2*inner  (reference formula, pinned rounding)
        float d2 = __fsub_rn(__fadd_rn(psq, qsq), __fmul_rn(2.0f, inner));
        A[t] = pack_key(d2, __float_as_int(q.w));
      }
      bitonic_sort16(A);
      merge_keep16(T, A);
      thr = unmap_hi((unsigned)(T[15] >> 32));
    }
  }

  u64* pb = pkey + ((size_t)(b * SPLIT + s) * KNN) * NPTS + pos;
#pragma unroll
  for (int j = 0; j < 16; ++j) pb[(size_t)j * NPTS] = T[j];
}

// ---------------------------------------------------------------------------
// Kernel 1b: merge SPLIT sorted lists -> top-16, then numpy-exact fp32 score
// (validated round 2). Keys carry ORIGINAL indices. Thread <-> sorted pos;
// score written to score[b][orig]. block 64 -> 512 blocks (was 128x256:
// half-idle chip).
// ---------------------------------------------------------------------------
__global__ __attribute__((amdgpu_waves_per_eu(1, 2)))
__launch_bounds__(64) void merge_score_kernel(
    const float* __restrict__ x, const float4* __restrict__ sorted4,
    const u64* __restrict__ pkey, float* __restrict__ score) {
  const int b = blockIdx.x / (NPTS / 64);
  const int pos = (blockIdx.x % (NPTS / 64)) * 64 + threadIdx.x;

  u64 T[16];
  {
    const u64* pb = pkey + ((size_t)(b * SPLIT + 0) * KNN) * NPTS + pos;
#pragma unroll
    for (int j = 0; j < 16; ++j) T[j] = pb[(size_t)j * NPTS];
  }
#pragma unroll
  for (int s = 1; s < SPLIT; ++s) {
    const u64* pb = pkey + ((size_t)(b * SPLIT + s) * KNN) * NPTS + pos;
    u64 A[16];
#pragma unroll
    for (int j = 0; j < 16; ++j) A[j] = pb[(size_t)j * NPTS];
    merge_keep16(T, A);
  }

  float4 p4 = sorted4[(size_t)b * NPTS + pos];
  const float ppx = p4.x, ppy = p4.y, ppz = p4.z;
  const int orig = __float_as_int(p4.w);
  const float* xb = x + (size_t)b * 3 * NPTS;

  float nx[KNN], ny[KNN], nz[KNN];
#pragma unroll
  for (int j = 0; j < KNN; ++j) {
    int idx = (int)(unsigned)T[j];
    nx[j] = xb[idx];
    ny[j] = xb[NPTS + idx];
    nz[j] = xb[2 * NPTS + idx];
  }

  // numpy fp32 pairwise sum over (3,16): per d, r_j = a_j + a_{j+8},
  // P_d = ((r0+r1)+(r2+r3)) + ((r4+r5)+(r6+r7)); score = (P0+P1)+P2.
  float P[3];
#pragma unroll
  for (int d = 0; d < 3; ++d) {
    const float pc = (d == 0) ? ppx : ((d == 1) ? ppy : ppz);
    float r[8];
#pragma unroll
    for (int j = 0; j < 8; ++j) {
      float c0 = (d == 0) ? nx[j] : ((d == 1) ? ny[j] : nz[j]);
      float c1 = (d == 0) ? nx[j + 8] : ((d == 1) ? ny[j + 8] : nz[j + 8]);
      float e0 = __fsub_rn(c0, pc);
      float e1 = __fsub_rn(c1, pc);
      r[j] = __fadd_rn(__fmul_rn(e0, e0), __fmul_rn(e1, e1));
    }
    float t0 = __fadd_rn(r[0], r[1]);
    float t1 = __fadd_rn(r[2], r[3]);
    float t2 = __fadd_rn(r[4], r[5]);
    float t3 = __fadd_rn(r[6], r[7]);
    P[d] = __fadd_rn(__fadd_rn(t0, t1), __fadd_rn(t2, t3));
  }
  score[(size_t)b * NPTS + orig] =
      __fadd_rn(__fadd_rn(P[0], P[1]), P[2]);
}

// ---------------------------------------------------------------------------
// Rank pipeline (original-index domain, unchanged semantics).
// ---------------------------------------------------------------------------
__global__ __launch_bounds__(256) void zero_kernel(int* __restrict__ cnt) {
  cnt[blockIdx.x * 256 + threadIdx.x] = 0;
}

__global__ __launch_bounds__(256) void rank_partial_kernel(
    const float* __restrict__ score, int* __restrict__ cnt) {
  const int s = blockIdx.x % RSPLIT;
  const int ntile = (blockIdx.x / RSPLIT) % (NPTS / 256);
  const int b = blockIdx.x / (RSPLIT * (NPTS / 256));
  __shared__ float ss[RCHUNK];
  const float* sb = score + (size_t)b * NPTS;
  for (int i = threadIdx.x; i < RCHUNK; i += 256)
    ss[i] = sb[s * RCHUNK + i];
  const int n = ntile * 256 + threadIdx.x;
  const float sn = sb[n];
  __syncthreads();
  int c = 0;
#pragma unroll 8
  for (int mm = 0; mm < RCHUNK; ++mm) {
    float sm = ss[mm];
    int gm = s * RCHUNK + mm;
    c += (sm > sn) || (sm == sn && gm < n);
  }
  atomicAdd(&cnt[(size_t)b * NPTS + n], c);
}

__global__ __launch_bounds__(256) void rank_scatter_kernel(
    const int* __restrict__ cnt, int* __restrict__ sel, int npts) {
  int t = blockIdx.x * 256 + threadIdx.x;
  int b = t / NPTS;
  int n = t % NPTS;
  int c = cnt[t];
  if (c < npts) sel[(size_t)b * npts + c] = n;
}

__global__ __launch_bounds__(256) void gather_kernel(
    const float* __restrict__ x, const float* __restrict__ y,
    const int* __restrict__ sel, float* __restrict__ out, int npts,
    int total0, int total) {
  int tid = blockIdx.x * blockDim.x + threadIdx.x;
  if (tid >= total) return;
  if (tid < total0) {
    int j = tid % npts;
    int rest = tid / npts;
    int d = rest % 3;
    int b = rest / 3;
    int src = sel[b * npts + j];
    out[tid] = x[((size_t)b * 3 + d) * NPTS + src];
  } else {
    int t = tid - total0;
    int j = t % npts;
    int rest = t / npts;
    int c = rest % CHAN;
    int b = rest / CHAN;
    int src = sel[b * npts + j];
    out[tid] = y[((size_t)b * CHAN + c) * NPTS + src];
  }
}

extern "C" void kernel_launch(void* const* d_in, const int* in_sizes, int n_in,
                              void* d_out, int out_size, void* d_ws,
                              size_t ws_size, hipStream_t stream) {
  const float* x = (const float*)d_in[0];
  const float* y = (const float*)d_in[1];
  float* out = (float*)d_out;

  const int npts = out_size / (BATCH * (3 + CHAN));

  // workspace layout (all 16B-aligned sizes):
  char* w = (char*)d_ws;
  u64* pkey = (u64*)w;                       // 16.78 MB
  w += sizeof(u64) * (size_t)BATCH * SPLIT * KNN * NPTS;
  float4* sorted4 = (float4*)w;              // 512 KB
  w += sizeof(float4) * (size_t)BATCH * NPTS;
  float* gmin = (float*)w;                   // 8 KB
  w += sizeof(float) * (size_t)BATCH * NGRP;
  float* gmax = (float*)w;                   // 8 KB
  w += sizeof(float) * (size_t)BATCH * NGRP;
  // xrank (early) aliases score (late): disjoint lifetimes
  int* xrank = (int*)w;
  float* score = (float*)w;                  // 128 KB
  w += sizeof(float) * (size_t)BATCH * NPTS;
  int* cnt = (int*)w;                        // 128 KB
  w += sizeof(int) * (size_t)BATCH * NPTS;
  int* sel = (int*)w;                        // 64 KB

  xrank_kernel<<<BATCH * (NPTS / 256), 256, 0, stream>>>(x, xrank);
  build_sorted_kernel<<<BATCH * NPTS / 256, 256, 0, stream>>>(
      x, xrank, sorted4);
  aabb_kernel<<<BATCH * NGRP / 256, 256, 0, stream>>>(sorted4, gmin, gmax);
  zero_kernel<<<BATCH * NPTS / 256, 256, 0, stream>>>(cnt);
  knn_sorted_kernel<<<BATCH * 16 * SPLIT, 256, 0, stream>>>(
      sorted4, gmin, gmax, pkey);
  merge_score_kernel<<<BATCH * (NPTS / 64), 64, 0, stream>>>(
      x, sorted4, pkey, score);
  rank_partial_kernel<<<BATCH * (NPTS / 256) * RSPLIT, 256, 0, stream>>>(
      score, cnt);
  rank_scatter_kernel<<<BATCH * NPTS / 256, 256, 0, stream>>>(cnt, sel, npts);

  const int total0 = BATCH * 3 * npts;
  gather_kernel<<<(out_size + 255) / 256, 256, 0, stream>>>(
      x, y, sel, out, npts, total0, out_size);
}